// Round 13
// baseline (251.592 us; speedup 1.0000x reference)
//
#include <hip/hip_runtime.h>

#define NN 50000
#define DD 128
#define NE 600000
#define NP 200000
#define NS 300000
#define NU 256
#define NBH 128
#define EPB 4688    // ceil(NE/NBH)
#define NW 12500    // NN/4 byte-packed words
#define NB64 782    // ceil(NN/64)
#define NSCAN 49    // ceil(NW/256) blocks own the row_ptr scan
#define AGG_TILES 1563              // ceil(NN/32)
#define AGG_GRID (((AGG_TILES + 1) / 2) * 8)   // 6256: 4 channel-groups x tiles, XCD-swizzled

typedef __attribute__((ext_vector_type(8))) short short8;
typedef __attribute__((ext_vector_type(4))) float floatx4;

__device__ inline float bf2f(unsigned int u16) {
    unsigned int x = u16 << 16;
    float f; __builtin_memcpy(&f, &x, 4); return f;
}
__device__ inline unsigned short f2bf(float f) {
    unsigned int x; __builtin_memcpy(&x, &f, 4);
    unsigned int lsb = (x >> 16) & 1u;
    x += 0x7fffu + lsb;
    return (unsigned short)(x >> 16);
}

// ---- per-block byte histograms: grid (NBH, 2); y=0 counts src, y=1 counts dst ----
__global__ __launch_bounds__(256) void k_hist(const int* __restrict__ ei,
                                              unsigned int* __restrict__ P,
                                              unsigned long long* __restrict__ status) {
    __shared__ unsigned int hw[NW];
    int b = blockIdx.x, half = blockIdx.y, tid = threadIdx.x;
    if (b == 0 && half == 0 && tid < 64) status[tid] = 0ull;
    for (int w = tid; w < NW; w += 256) hw[w] = 0;
    __syncthreads();
    const int* src = ei + (size_t)half * NE;
    int e0 = b * EPB, e1 = min(e0 + EPB, NE);
    for (int e = e0 + tid; e < e1; e += 256) {
        int s = src[e];
        atomicAdd(&hw[s >> 2], 1u << ((s & 3) * 8));
    }
    __syncthreads();
    unsigned int* Pb = P + ((size_t)half * NBH + b) * NW;
    for (int w = tid; w < NW; w += 256) Pb[w] = hw[w];
}

// ---- fused mid-chain: reduce+rsqrt, weight cast, row_ptr scan (decoupled
// lookback over 49 block partials), colscan byte-bases. One dispatch. ----
__global__ __launch_bounds__(256) void k_mid(
    const unsigned int* __restrict__ P_hist, float* __restrict__ r,
    const float* __restrict__ W1, const float* __restrict__ W2, const float* __restrict__ dW,
    unsigned short* __restrict__ BT1, unsigned short* __restrict__ BT2,
    unsigned short* __restrict__ BTd,
    int* __restrict__ row_ptr, unsigned char* __restrict__ baseb,
    unsigned long long* __restrict__ status)
{
    int b = blockIdx.x, tid = threadIdx.x, lane = tid & 63, w = tid >> 6;
    int gid = b * 256 + tid;

    // ---- phase A: reduce histogram columns -> counts + rsqrt ----
    int4 v = {0, 0, 0, 0};
    if (gid < NW) {                          // dst half: keep counts for scan, write r_in
        const unsigned int* Ph = P_hist + (size_t)NBH * NW + gid;
        int c0 = 0, c1 = 0, c2 = 0, c3 = 0;
        for (int b2 = 0; b2 < NBH; ++b2) {
            unsigned int x = Ph[(size_t)b2 * NW];
            c0 += x & 0xff; c1 += (x >> 8) & 0xff; c2 += (x >> 16) & 0xff; c3 += x >> 24;
        }
        v = (int4){c0, c1, c2, c3};
        float4 rr = {rsqrtf((float)max(c0, 1)), rsqrtf((float)max(c1, 1)),
                     rsqrtf((float)max(c2, 1)), rsqrtf((float)max(c3, 1))};
        *(float4*)(r + NN + gid * 4) = rr;
    } else if (gid < 2 * NW) {               // src half: write r_out
        int wl = gid - NW;
        const unsigned int* Ph = P_hist + wl;
        int c0 = 0, c1 = 0, c2 = 0, c3 = 0;
        for (int b2 = 0; b2 < NBH; ++b2) {
            unsigned int x = Ph[(size_t)b2 * NW];
            c0 += x & 0xff; c1 += (x >> 8) & 0xff; c2 += (x >> 16) & 0xff; c3 += x >> 24;
        }
        float4 rr = {rsqrtf((float)max(c0, 1)), rsqrtf((float)max(c1, 1)),
                     rsqrtf((float)max(c2, 1)), rsqrtf((float)max(c3, 1))};
        *(float4*)(r + wl * 4) = rr;
    }

    // ---- phase B: weight transpose + bf16 cast ----
    {
        int t = gid;
        if (t < 16384) { int rr = t >> 7, cc = t & 127; BT1[cc * 128 + rr] = f2bf(W1[t]); }
        else if (t < 32768) { int t2 = t - 16384; int rr = t2 >> 7, cc = t2 & 127; BT2[cc * 128 + rr] = f2bf(W2[t2]); }
        else if (t < 65536) { int t2 = t - 32768; int rr = t2 >> 8, cc = t2 & 255; BTd[cc * 128 + rr] = f2bf(dW[t2]); }
    }

    // ---- phase C: scan blocks (0..48) build row_ptr via decoupled lookback ----
    if (b < NSCAN) {
        __shared__ int wsum[4];
        __shared__ long long sbase;
        int tot = v.x + v.y + v.z + v.w;
        int x = tot;
#pragma unroll
        for (int off = 1; off < 64; off <<= 1) {
            int y = __shfl_up(x, off);
            if (lane >= off) x += y;
        }
        if (lane == 63) wsum[w] = x;
        __syncthreads();
        int woff = 0;
#pragma unroll
        for (int i = 0; i < 4; ++i) if (i < w) woff += wsum[i];
        if (tid == 0) {
            int btot = wsum[0] + wsum[1] + wsum[2] + wsum[3];
            if (b == 0) {
                sbase = 0;
                __threadfence();
                atomicExch(&status[0], (2ull << 62) | (unsigned long long)btot);
            } else {
                __threadfence();
                atomicExch(&status[b], (1ull << 62) | (unsigned long long)btot);
                long long run = 0; int j = b - 1;
                while (true) {
                    unsigned long long s;
                    do { s = atomicAdd(&status[j], 0ull); } while (s == 0ull);
                    run += (long long)(s & 0x3fffffffffffffffull);
                    if ((s >> 62) == 2ull) break;
                    --j;
                }
                sbase = run;
                __threadfence();
                atomicExch(&status[b], (2ull << 62) | (unsigned long long)(run + btot));
            }
        }
        __syncthreads();
        if (gid < NW) {
            int base = (int)sbase + woff + (x - tot);
            int4 o = {base, base + v.x, base + v.x + v.y, base + v.x + v.y + v.z};
            *(int4*)(row_ptr + gid * 4) = o;
        }
        if (b == 0 && tid == 0) row_ptr[NN] = NE;
    }

    // ---- phase D: colscan byte-bases (blocks NSCAN..NSCAN+195) ----
    int cb = b - NSCAN;
    if (cb >= 0 && cb < 196) {
        int n = cb * 256 + tid;
        if (n < NN) {
            int wl = n >> 2, sh = (n & 3) * 8;
            int run = 0;
            const unsigned int* Pd = P_hist + (size_t)NBH * NW;
            for (int b2 = 0; b2 < NBH; ++b2) {
                baseb[(size_t)b2 * NN + n] = (unsigned char)run;
                run += (Pd[(size_t)b2 * NW + wl] >> sh) & 0xff;
            }
        }
    }
}

// ---- wide kernel: blocks 0..NBH-1 bucket edges; blocks NBH.. do layer-1 GEMM ----
__global__ __launch_bounds__(256) void k_gemm1_bucket(
    const float* __restrict__ A, const float* __restrict__ rs,
    const unsigned short* __restrict__ BT, unsigned short* __restrict__ Cm,
    const int* __restrict__ ei, const int* __restrict__ row_ptr,
    const unsigned char* __restrict__ baseb, int* __restrict__ col)
{
    __shared__ unsigned short sm[26112];   // 52224 B: GEMM tiles / bucket cursors (union)
    int b = blockIdx.x, tid = threadIdx.x;

    if (b < NBH) {
        // ---- bucket role ----
        unsigned int* cw = (unsigned int*)sm;
        for (int w = tid; w < NW; w += 256) cw[w] = 0;
        __syncthreads();
        const unsigned char* bt = baseb + (size_t)b * NN;
        int e0 = b * EPB, e1 = min(e0 + EPB, NE);
        for (int e = e0 + tid; e < e1; e += 256) {
            int s = ei[e], d = ei[NE + e];
            int sh = (d & 3) * 8;
            unsigned int old = atomicAdd(&cw[d >> 2], 1u << sh);
            col[row_ptr[d] + (int)bt[d] + ((old >> sh) & 0xff)] = s;
        }
        return;
    }

    // ---- GEMM role: t = (bf16(A_f32) @ W1) * r_out ----
    unsigned short (*As)[136] = (unsigned short(*)[136])sm;
    unsigned short (*Bs)[136] = (unsigned short(*)[136])(sm + 64 * 136);
    int lane = tid & 63, wave = tid >> 6;
    int quad = lane >> 4, l16 = lane & 15;
    int row0 = (b - NBH) * 64;

#pragma unroll
    for (int p = 0; p < 8; ++p) {
        int fid = tid + p * 256;
        int r = fid >> 5, c = fid & 31;
        int gr = row0 + r; if (gr > NN - 1) gr = NN - 1;
        float4 v = *(const float4*)(A + (size_t)gr * DD + c * 4);
        ushort4 u;
        u.x = f2bf(v.x); u.y = f2bf(v.y); u.z = f2bf(v.z); u.w = f2bf(v.w);
        *(ushort4*)&As[r][c * 4] = u;
    }
#pragma unroll
    for (int p = 0; p < 8; ++p) {
        int fid = tid + p * 256;
        int r = fid >> 4, c = fid & 15;
        *(uint4*)&Bs[r][c * 8] = *(const uint4*)(BT + (size_t)r * DD + c * 8);
    }
    __syncthreads();

    short8 af[4];
#pragma unroll
    for (int ks = 0; ks < 4; ++ks)
        af[ks] = *(const short8*)&As[wave * 16 + l16][ks * 32 + quad * 8];
    floatx4 acc[8];
#pragma unroll
    for (int nt = 0; nt < 8; ++nt) acc[nt] = (floatx4){0.f, 0.f, 0.f, 0.f};
#pragma unroll
    for (int ks = 0; ks < 4; ++ks) {
#pragma unroll
        for (int nt = 0; nt < 8; ++nt) {
            short8 bf = *(const short8*)&Bs[nt * 16 + l16][ks * 32 + quad * 8];
            acc[nt] = __builtin_amdgcn_mfma_f32_16x16x32_bf16(af[ks], bf, acc[nt], 0, 0, 0);
        }
    }
    int rbase = row0 + wave * 16 + quad * 4;
#pragma unroll
    for (int r = 0; r < 4; ++r) {
        int gr = rbase + r;
        if (gr < NN) {
            float s = rs[gr];
#pragma unroll
            for (int nt = 0; nt < 8; ++nt)
                Cm[(size_t)gr * DD + nt * 16 + l16] = f2bf(acc[nt][r] * s);
        }
    }
}

// ---- MFMA GEMM (layer 2): Cm = rowscale(A_bf16 @ W2) ----
__global__ __launch_bounds__(256) void k_gemm_bf(const unsigned short* __restrict__ A,
                                                 const float* __restrict__ rs,
                                                 const unsigned short* __restrict__ BT,
                                                 unsigned short* __restrict__ Cm) {
    __shared__ unsigned short As[64][136];
    __shared__ unsigned short Bs[128][136];
    int tid = threadIdx.x, lane = tid & 63, wave = tid >> 6;
    int quad = lane >> 4, l16 = lane & 15;
    int row0 = blockIdx.x * 64;

#pragma unroll
    for (int p = 0; p < 4; ++p) {
        int fid = tid + p * 256;
        int r = fid >> 4, c = fid & 15;
        int gr = row0 + r; if (gr > NN - 1) gr = NN - 1;
        *(uint4*)&As[r][c * 8] = *(const uint4*)(A + (size_t)gr * DD + c * 8);
    }
#pragma unroll
    for (int p = 0; p < 8; ++p) {
        int fid = tid + p * 256;
        int r = fid >> 4, c = fid & 15;
        *(uint4*)&Bs[r][c * 8] = *(const uint4*)(BT + (size_t)r * DD + c * 8);
    }
    __syncthreads();

    short8 af[4];
#pragma unroll
    for (int ks = 0; ks < 4; ++ks)
        af[ks] = *(const short8*)&As[wave * 16 + l16][ks * 32 + quad * 8];
    floatx4 acc[8];
#pragma unroll
    for (int nt = 0; nt < 8; ++nt) acc[nt] = (floatx4){0.f, 0.f, 0.f, 0.f};
#pragma unroll
    for (int ks = 0; ks < 4; ++ks) {
#pragma unroll
        for (int nt = 0; nt < 8; ++nt) {
            short8 bf = *(const short8*)&Bs[nt * 16 + l16][ks * 32 + quad * 8];
            acc[nt] = __builtin_amdgcn_mfma_f32_16x16x32_bf16(af[ks], bf, acc[nt], 0, 0, 0);
        }
    }
    int rbase = row0 + wave * 16 + quad * 4;
#pragma unroll
    for (int r = 0; r < 4; ++r) {
        int gr = rbase + r;
        if (gr < NN) {
            float s = rs[gr];
#pragma unroll
            for (int nt = 0; nt < 8; ++nt)
                Cm[(size_t)gr * DD + nt * 16 + l16] = f2bf(acc[nt][r] * s);
        }
    }
}

// ---- CSR aggregate, XCD-swizzled channel partitioning ----
// 4 channel-groups of 32 ch (64 B = 1 cache line per row-slice, 3.2 MB/group).
// blockIdx&7 = XCD slot (round-robin heuristic); slot>>1 = group -> each XCD's
// L2 caches only one group's slice. 8 lanes/node (uint2), 8 nodes/wave.
__global__ __launch_bounds__(256) void k_aggregate(const unsigned short* __restrict__ T,
                                                   const int* __restrict__ row_ptr,
                                                   const int* __restrict__ col,
                                                   const float* __restrict__ r_in,
                                                   const float* __restrict__ bias,
                                                   unsigned short* __restrict__ H) {
    int b = blockIdx.x;
    int slot = b & 7;
    int grp = slot >> 1;
    int tile = (b >> 3) * 2 + (slot & 1);
    int wave = threadIdx.x >> 6, lane = threadIdx.x & 63;
    int sub = lane >> 3, l8 = lane & 7;
    int node = tile * 32 + wave * 8 + sub;
    if (node >= NN) return;
    int cbase = grp * 32 + l8 * 4;          // 4 channels (8 B) per lane
    int beg = row_ptr[node], end = row_ptr[node + 1];
    float a0 = 0.f, a1 = 0.f, a2 = 0.f, a3 = 0.f;
    for (int base = beg; base < end; base += 8) {
        int m = end - base; if (m > 8) m = 8;
        int myidx = (l8 < m) ? col[base + l8] : 0;
        int j = 0;
        for (; j + 4 <= m; j += 4) {
            int s0 = __shfl(myidx, (sub << 3) | j);
            int s1 = __shfl(myidx, (sub << 3) | (j + 1));
            int s2 = __shfl(myidx, (sub << 3) | (j + 2));
            int s3 = __shfl(myidx, (sub << 3) | (j + 3));
            uint2 v0 = *(const uint2*)(T + (size_t)s0 * DD + cbase);
            uint2 v1 = *(const uint2*)(T + (size_t)s1 * DD + cbase);
            uint2 v2 = *(const uint2*)(T + (size_t)s2 * DD + cbase);
            uint2 v3 = *(const uint2*)(T + (size_t)s3 * DD + cbase);
            a0 += bf2f(v0.x & 0xffff) + bf2f(v1.x & 0xffff) + bf2f(v2.x & 0xffff) + bf2f(v3.x & 0xffff);
            a1 += bf2f(v0.x >> 16)    + bf2f(v1.x >> 16)    + bf2f(v2.x >> 16)    + bf2f(v3.x >> 16);
            a2 += bf2f(v0.y & 0xffff) + bf2f(v1.y & 0xffff) + bf2f(v2.y & 0xffff) + bf2f(v3.y & 0xffff);
            a3 += bf2f(v0.y >> 16)    + bf2f(v1.y >> 16)    + bf2f(v2.y >> 16)    + bf2f(v3.y >> 16);
        }
        for (; j < m; ++j) {
            int s0 = __shfl(myidx, (sub << 3) | j);
            uint2 v0 = *(const uint2*)(T + (size_t)s0 * DD + cbase);
            a0 += bf2f(v0.x & 0xffff); a1 += bf2f(v0.x >> 16);
            a2 += bf2f(v0.y & 0xffff); a3 += bf2f(v0.y >> 16);
        }
    }
    float rv = r_in[node];
    float4 bb = *(const float4*)(bias + cbase);
    uint2 w;
    w.x = (unsigned int)f2bf(a0 * rv + bb.x) | ((unsigned int)f2bf(a1 * rv + bb.y) << 16);
    w.y = (unsigned int)f2bf(a2 * rv + bb.z) | ((unsigned int)f2bf(a3 * rv + bb.w) << 16);
    *(uint2*)(H + (size_t)node * DD + cbase) = w;
}

// ---- MFMA MLP: P[n] = softmax(relu(h2[n]@dW + db)@oW + ob) ----
__global__ __launch_bounds__(256) void k_mlp_mfma(const unsigned short* __restrict__ H2,
                                                  const unsigned short* __restrict__ BTd,
                                                  const float* __restrict__ db,
                                                  const float* __restrict__ oW,
                                                  const float* __restrict__ ob,
                                                  float* __restrict__ P) {
    __shared__ unsigned short As[64][136];
    __shared__ unsigned short Bs[128][136];
    int tid = threadIdx.x, lane = tid & 63, wave = tid >> 6;
    int quad = lane >> 4, l16 = lane & 15;
    int row0 = blockIdx.x * 64;
#pragma unroll
    for (int p = 0; p < 4; ++p) {
        int fid = tid + p * 256;
        int r = fid >> 4, c = fid & 15;
        int gr = row0 + r; if (gr > NN - 1) gr = NN - 1;
        *(uint4*)&As[r][c * 8] = *(const uint4*)(H2 + (size_t)gr * DD + c * 8);
    }
    short8 af[4];
    floatx4 acc[16];
#pragma unroll
    for (int i = 0; i < 16; ++i) acc[i] = (floatx4){0.f, 0.f, 0.f, 0.f};

    for (int ch = 0; ch < 2; ++ch) {
        __syncthreads();
#pragma unroll
        for (int p = 0; p < 8; ++p) {
            int fid = tid + p * 256;
            int r = fid >> 4, c = fid & 15;
            *(uint4*)&Bs[r][c * 8] = *(const uint4*)(BTd + (size_t)(ch * 128 + r) * DD + c * 8);
        }
        __syncthreads();
        if (ch == 0) {
#pragma unroll
            for (int ks = 0; ks < 4; ++ks)
                af[ks] = *(const short8*)&As[wave * 16 + l16][ks * 32 + quad * 8];
        }
#pragma unroll
        for (int ks = 0; ks < 4; ++ks) {
#pragma unroll
            for (int nt = 0; nt < 8; ++nt) {
                short8 bf = *(const short8*)&Bs[nt * 16 + l16][ks * 32 + quad * 8];
                acc[ch * 8 + nt] =
                    __builtin_amdgcn_mfma_f32_16x16x32_bf16(af[ks], bf, acc[ch * 8 + nt], 0, 0, 0);
            }
        }
    }
    int rbase = row0 + wave * 16 + quad * 4;
#pragma unroll
    for (int r = 0; r < 4; ++r) {
        float p0 = 0.f, p1 = 0.f;
#pragma unroll
        for (int ch = 0; ch < 2; ++ch) {
#pragma unroll
            for (int nt = 0; nt < 8; ++nt) {
                int colc = ch * 128 + nt * 16 + l16;
                float h = acc[ch * 8 + nt][r] + db[colc];
                h = fmaxf(h, 0.f);
                p0 += h * oW[2 * colc];
                p1 += h * oW[2 * colc + 1];
            }
        }
#pragma unroll
        for (int m = 8; m >= 1; m >>= 1) {
            p0 += __shfl_xor(p0, m, 16);
            p1 += __shfl_xor(p1, m, 16);
        }
        if (l16 == 0) {
            int gr = rbase + r;
            if (gr < NN) {
                float l0 = p0 + ob[0], l1 = p1 + ob[1];
                float mx = fmaxf(l0, l1);
                float e0 = __expf(l0 - mx), e1 = __expf(l1 - mx);
                float inv = 1.f / (e0 + e1);
                float2 pr = {e0 * inv, e1 * inv};
                *(float2*)(P + 2 * gr) = pr;
            }
        }
    }
}

// ---- final gather ----
__global__ void k_gather(const int* __restrict__ sidx, const int* __restrict__ oe,
                         const float* __restrict__ P, float* __restrict__ out) {
    int i = blockIdx.x * 256 + threadIdx.x;
    if (i >= NS) return;
    int node = oe[sidx[i]];
    float2 v = *(const float2*)(P + 2 * node);
    *(float2*)(out + 2 * i) = v;
}

extern "C" void kernel_launch(void* const* d_in, const int* in_sizes, int n_in,
                              void* d_out, int out_size, void* d_ws, size_t ws_size,
                              hipStream_t stream) {
    const float* node_state = (const float*)d_in[0];
    const int* ei   = (const int*)d_in[1];
    const int* oe   = (const int*)d_in[2];
    const int* sidx = (const int*)d_in[3];
    const float* W1 = (const float*)d_in[4];
    const float* b1 = (const float*)d_in[5];
    const float* W2 = (const float*)d_in[6];
    const float* b2 = (const float*)d_in[7];
    const float* dW = (const float*)d_in[8];
    const float* db = (const float*)d_in[9];
    const float* oW = (const float*)d_in[10];
    const float* ob = (const float*)d_in[11];
    float* out = (float*)d_out;

    char* ws = (char*)d_ws;
    size_t off = 0;
    auto carve = [&](size_t bytes) -> char* {
        char* p = ws + off;
        off = (off + bytes + 255) & ~(size_t)255;
        return p;
    };
    float* r       = (float*)carve((size_t)2 * NN * 4);
    int*   row_ptr = (int*)carve((size_t)(NN + 1) * 4);
    int*   col     = (int*)carve((size_t)NE * 4);
    unsigned int* P_hist = (unsigned int*)carve((size_t)2 * NBH * NW * 4);
    unsigned char* baseb = (unsigned char*)carve((size_t)NBH * NN);
    unsigned long long* status = (unsigned long long*)carve(64 * 8);
    unsigned short* t   = (unsigned short*)carve((size_t)NN * DD * 2);
    unsigned short* h   = (unsigned short*)carve((size_t)NN * DD * 2);
    unsigned short* BT1 = (unsigned short*)carve((size_t)DD * DD * 2);
    unsigned short* BT2 = (unsigned short*)carve((size_t)DD * DD * 2);
    unsigned short* BTd = (unsigned short*)carve((size_t)DD * NU * 2);
    float* P = (float*)t;   // alias: t dead after second aggregate

    float* r_out = r;
    float* r_in  = r + NN;

    // CSR build — no global atomics; mid-chain fused into one dispatch
    k_hist<<<dim3(NBH, 2), 256, 0, stream>>>(ei, P_hist, status);
    k_mid<<<256, 256, 0, stream>>>(P_hist, r, W1, W2, dW, BT1, BT2, BTd,
                                   row_ptr, baseb, status);

    // bucket + layer-1 GEMM in one wide kernel (independent given k_mid)
    k_gemm1_bucket<<<NBH + NB64, 256, 0, stream>>>(node_state, r_out, BT1, t,
                                                   ei, row_ptr, baseb, col);
    k_aggregate<<<AGG_GRID, 256, 0, stream>>>(t, row_ptr, col, r_in, b1, h);

    // layer 2
    k_gemm_bf<<<NB64, 256, 0, stream>>>(h, r_out, BT2, t);
    k_aggregate<<<AGG_GRID, 256, 0, stream>>>(t, row_ptr, col, r_in, b2, h);

    // per-node MLP + softmax, then gather
    k_mlp_mfma<<<NB64, 256, 0, stream>>>(h, BTd, db, oW, ob, P);
    k_gather<<<(NS + 255) / 256, 256, 0, stream>>>(sidx, oe, P, out);
}

// Round 14
// 233.687 us; speedup vs baseline: 1.0766x; 1.0766x over previous
//
#include <hip/hip_runtime.h>

#define NN 50000
#define DD 128
#define NE 600000
#define NP 200000
#define NS 300000
#define NU 256
#define NBH 128
#define EPB 4688    // ceil(NE/NBH)
#define NW 12500    // NN/4 byte-packed words
#define NB64 782    // ceil(NN/64)
#define NSCAN 49    // ceil(NW/256) blocks own the row_ptr scan

typedef __attribute__((ext_vector_type(8))) short short8;
typedef __attribute__((ext_vector_type(4))) float floatx4;

__device__ inline float bf2f(unsigned int u16) {
    unsigned int x = u16 << 16;
    float f; __builtin_memcpy(&f, &x, 4); return f;
}
__device__ inline unsigned short f2bf(float f) {
    unsigned int x; __builtin_memcpy(&x, &f, 4);
    unsigned int lsb = (x >> 16) & 1u;
    x += 0x7fffu + lsb;
    return (unsigned short)(x >> 16);
}

// ---- per-block byte histograms: grid (NBH, 2); y=0 counts src, y=1 counts dst ----
__global__ __launch_bounds__(256) void k_hist(const int* __restrict__ ei,
                                              unsigned int* __restrict__ P,
                                              unsigned long long* __restrict__ status) {
    __shared__ unsigned int hw[NW];
    int b = blockIdx.x, half = blockIdx.y, tid = threadIdx.x;
    if (b == 0 && half == 0 && tid < 64) status[tid] = 0ull;
    for (int w = tid; w < NW; w += 256) hw[w] = 0;
    __syncthreads();
    const int* src = ei + (size_t)half * NE;
    int e0 = b * EPB, e1 = min(e0 + EPB, NE);
    for (int e = e0 + tid; e < e1; e += 256) {
        int s = src[e];
        atomicAdd(&hw[s >> 2], 1u << ((s & 3) * 8));
    }
    __syncthreads();
    unsigned int* Pb = P + ((size_t)half * NBH + b) * NW;
    for (int w = tid; w < NW; w += 256) Pb[w] = hw[w];
}

// ---- fused mid-chain: reduce+rsqrt, weight cast, row_ptr scan (decoupled
// lookback over 49 block partials), colscan byte-bases. One dispatch. ----
__global__ __launch_bounds__(256) void k_mid(
    const unsigned int* __restrict__ P_hist, float* __restrict__ r,
    const float* __restrict__ W1, const float* __restrict__ W2, const float* __restrict__ dW,
    unsigned short* __restrict__ BT1, unsigned short* __restrict__ BT2,
    unsigned short* __restrict__ BTd,
    int* __restrict__ row_ptr, unsigned char* __restrict__ baseb,
    unsigned long long* __restrict__ status)
{
    int b = blockIdx.x, tid = threadIdx.x, lane = tid & 63, w = tid >> 6;
    int gid = b * 256 + tid;

    // ---- phase A: reduce histogram columns -> counts + rsqrt ----
    int4 v = {0, 0, 0, 0};
    if (gid < NW) {                          // dst half: keep counts for scan, write r_in
        const unsigned int* Ph = P_hist + (size_t)NBH * NW + gid;
        int c0 = 0, c1 = 0, c2 = 0, c3 = 0;
        for (int b2 = 0; b2 < NBH; ++b2) {
            unsigned int x = Ph[(size_t)b2 * NW];
            c0 += x & 0xff; c1 += (x >> 8) & 0xff; c2 += (x >> 16) & 0xff; c3 += x >> 24;
        }
        v = (int4){c0, c1, c2, c3};
        float4 rr = {rsqrtf((float)max(c0, 1)), rsqrtf((float)max(c1, 1)),
                     rsqrtf((float)max(c2, 1)), rsqrtf((float)max(c3, 1))};
        *(float4*)(r + NN + gid * 4) = rr;
    } else if (gid < 2 * NW) {               // src half: write r_out
        int wl = gid - NW;
        const unsigned int* Ph = P_hist + wl;
        int c0 = 0, c1 = 0, c2 = 0, c3 = 0;
        for (int b2 = 0; b2 < NBH; ++b2) {
            unsigned int x = Ph[(size_t)b2 * NW];
            c0 += x & 0xff; c1 += (x >> 8) & 0xff; c2 += (x >> 16) & 0xff; c3 += x >> 24;
        }
        float4 rr = {rsqrtf((float)max(c0, 1)), rsqrtf((float)max(c1, 1)),
                     rsqrtf((float)max(c2, 1)), rsqrtf((float)max(c3, 1))};
        *(float4*)(r + wl * 4) = rr;
    }

    // ---- phase B: weight transpose + bf16 cast ----
    {
        int t = gid;
        if (t < 16384) { int rr = t >> 7, cc = t & 127; BT1[cc * 128 + rr] = f2bf(W1[t]); }
        else if (t < 32768) { int t2 = t - 16384; int rr = t2 >> 7, cc = t2 & 127; BT2[cc * 128 + rr] = f2bf(W2[t2]); }
        else if (t < 65536) { int t2 = t - 32768; int rr = t2 >> 8, cc = t2 & 255; BTd[cc * 128 + rr] = f2bf(dW[t2]); }
    }

    // ---- phase C: scan blocks (0..48) build row_ptr via decoupled lookback ----
    if (b < NSCAN) {
        __shared__ int wsum[4];
        __shared__ long long sbase;
        int tot = v.x + v.y + v.z + v.w;
        int x = tot;
#pragma unroll
        for (int off = 1; off < 64; off <<= 1) {
            int y = __shfl_up(x, off);
            if (lane >= off) x += y;
        }
        if (lane == 63) wsum[w] = x;
        __syncthreads();
        int woff = 0;
#pragma unroll
        for (int i = 0; i < 4; ++i) if (i < w) woff += wsum[i];
        if (tid == 0) {
            int btot = wsum[0] + wsum[1] + wsum[2] + wsum[3];
            if (b == 0) {
                sbase = 0;
                __threadfence();
                atomicExch(&status[0], (2ull << 62) | (unsigned long long)btot);
            } else {
                __threadfence();
                atomicExch(&status[b], (1ull << 62) | (unsigned long long)btot);
                long long run = 0; int j = b - 1;
                while (true) {
                    unsigned long long s;
                    do { s = atomicAdd(&status[j], 0ull); } while (s == 0ull);
                    run += (long long)(s & 0x3fffffffffffffffull);
                    if ((s >> 62) == 2ull) break;
                    --j;
                }
                sbase = run;
                __threadfence();
                atomicExch(&status[b], (2ull << 62) | (unsigned long long)(run + btot));
            }
        }
        __syncthreads();
        if (gid < NW) {
            int base = (int)sbase + woff + (x - tot);
            int4 o = {base, base + v.x, base + v.x + v.y, base + v.x + v.y + v.z};
            *(int4*)(row_ptr + gid * 4) = o;
        }
        if (b == 0 && tid == 0) row_ptr[NN] = NE;
    }

    // ---- phase D: colscan byte-bases (blocks NSCAN..NSCAN+195) ----
    int cb = b - NSCAN;
    if (cb >= 0 && cb < 196) {
        int n = cb * 256 + tid;
        if (n < NN) {
            int wl = n >> 2, sh = (n & 3) * 8;
            int run = 0;
            const unsigned int* Pd = P_hist + (size_t)NBH * NW;
            for (int b2 = 0; b2 < NBH; ++b2) {
                baseb[(size_t)b2 * NN + n] = (unsigned char)run;
                run += (Pd[(size_t)b2 * NW + wl] >> sh) & 0xff;
            }
        }
    }
}

// ---- wide kernel: blocks 0..NBH-1 bucket edges; blocks NBH.. do layer-1 GEMM ----
__global__ __launch_bounds__(256) void k_gemm1_bucket(
    const float* __restrict__ A, const float* __restrict__ rs,
    const unsigned short* __restrict__ BT, unsigned short* __restrict__ Cm,
    const int* __restrict__ ei, const int* __restrict__ row_ptr,
    const unsigned char* __restrict__ baseb, int* __restrict__ col)
{
    __shared__ unsigned short sm[26112];   // 52224 B: GEMM tiles / bucket cursors (union)
    int b = blockIdx.x, tid = threadIdx.x;

    if (b < NBH) {
        // ---- bucket role ----
        unsigned int* cw = (unsigned int*)sm;
        for (int w = tid; w < NW; w += 256) cw[w] = 0;
        __syncthreads();
        const unsigned char* bt = baseb + (size_t)b * NN;
        int e0 = b * EPB, e1 = min(e0 + EPB, NE);
        for (int e = e0 + tid; e < e1; e += 256) {
            int s = ei[e], d = ei[NE + e];
            int sh = (d & 3) * 8;
            unsigned int old = atomicAdd(&cw[d >> 2], 1u << sh);
            col[row_ptr[d] + (int)bt[d] + ((old >> sh) & 0xff)] = s;
        }
        return;
    }

    // ---- GEMM role: t = (bf16(A_f32) @ W1) * r_out ----
    unsigned short (*As)[136] = (unsigned short(*)[136])sm;
    unsigned short (*Bs)[136] = (unsigned short(*)[136])(sm + 64 * 136);
    int lane = tid & 63, wave = tid >> 6;
    int quad = lane >> 4, l16 = lane & 15;
    int row0 = (b - NBH) * 64;

#pragma unroll
    for (int p = 0; p < 8; ++p) {
        int fid = tid + p * 256;
        int r = fid >> 5, c = fid & 31;
        int gr = row0 + r; if (gr > NN - 1) gr = NN - 1;
        float4 v = *(const float4*)(A + (size_t)gr * DD + c * 4);
        ushort4 u;
        u.x = f2bf(v.x); u.y = f2bf(v.y); u.z = f2bf(v.z); u.w = f2bf(v.w);
        *(ushort4*)&As[r][c * 4] = u;
    }
#pragma unroll
    for (int p = 0; p < 8; ++p) {
        int fid = tid + p * 256;
        int r = fid >> 4, c = fid & 15;
        *(uint4*)&Bs[r][c * 8] = *(const uint4*)(BT + (size_t)r * DD + c * 8);
    }
    __syncthreads();

    short8 af[4];
#pragma unroll
    for (int ks = 0; ks < 4; ++ks)
        af[ks] = *(const short8*)&As[wave * 16 + l16][ks * 32 + quad * 8];
    floatx4 acc[8];
#pragma unroll
    for (int nt = 0; nt < 8; ++nt) acc[nt] = (floatx4){0.f, 0.f, 0.f, 0.f};
#pragma unroll
    for (int ks = 0; ks < 4; ++ks) {
#pragma unroll
        for (int nt = 0; nt < 8; ++nt) {
            short8 bf = *(const short8*)&Bs[nt * 16 + l16][ks * 32 + quad * 8];
            acc[nt] = __builtin_amdgcn_mfma_f32_16x16x32_bf16(af[ks], bf, acc[nt], 0, 0, 0);
        }
    }
    int rbase = row0 + wave * 16 + quad * 4;
#pragma unroll
    for (int r = 0; r < 4; ++r) {
        int gr = rbase + r;
        if (gr < NN) {
            float s = rs[gr];
#pragma unroll
            for (int nt = 0; nt < 8; ++nt)
                Cm[(size_t)gr * DD + nt * 16 + l16] = f2bf(acc[nt][r] * s);
        }
    }
}

// ---- MFMA GEMM (layer 2): Cm = rowscale(A_bf16 @ W2) ----
__global__ __launch_bounds__(256) void k_gemm_bf(const unsigned short* __restrict__ A,
                                                 const float* __restrict__ rs,
                                                 const unsigned short* __restrict__ BT,
                                                 unsigned short* __restrict__ Cm) {
    __shared__ unsigned short As[64][136];
    __shared__ unsigned short Bs[128][136];
    int tid = threadIdx.x, lane = tid & 63, wave = tid >> 6;
    int quad = lane >> 4, l16 = lane & 15;
    int row0 = blockIdx.x * 64;

#pragma unroll
    for (int p = 0; p < 4; ++p) {
        int fid = tid + p * 256;
        int r = fid >> 4, c = fid & 15;
        int gr = row0 + r; if (gr > NN - 1) gr = NN - 1;
        *(uint4*)&As[r][c * 8] = *(const uint4*)(A + (size_t)gr * DD + c * 8);
    }
#pragma unroll
    for (int p = 0; p < 8; ++p) {
        int fid = tid + p * 256;
        int r = fid >> 4, c = fid & 15;
        *(uint4*)&Bs[r][c * 8] = *(const uint4*)(BT + (size_t)r * DD + c * 8);
    }
    __syncthreads();

    short8 af[4];
#pragma unroll
    for (int ks = 0; ks < 4; ++ks)
        af[ks] = *(const short8*)&As[wave * 16 + l16][ks * 32 + quad * 8];
    floatx4 acc[8];
#pragma unroll
    for (int nt = 0; nt < 8; ++nt) acc[nt] = (floatx4){0.f, 0.f, 0.f, 0.f};
#pragma unroll
    for (int ks = 0; ks < 4; ++ks) {
#pragma unroll
        for (int nt = 0; nt < 8; ++nt) {
            short8 bf = *(const short8*)&Bs[nt * 16 + l16][ks * 32 + quad * 8];
            acc[nt] = __builtin_amdgcn_mfma_f32_16x16x32_bf16(af[ks], bf, acc[nt], 0, 0, 0);
        }
    }
    int rbase = row0 + wave * 16 + quad * 4;
#pragma unroll
    for (int r = 0; r < 4; ++r) {
        int gr = rbase + r;
        if (gr < NN) {
            float s = rs[gr];
#pragma unroll
            for (int nt = 0; nt < 8; ++nt)
                Cm[(size_t)gr * DD + nt * 16 + l16] = f2bf(acc[nt][r] * s);
        }
    }
}

// ---- CSR aggregate + fused finalize: H[n] = bf16((sum T[s]) * r_in[n] + b) ----
// 16 lanes/node, uint4/lane; up to 8 gathers in flight (avg degree ~12).
__global__ __launch_bounds__(256) void k_aggregate(const unsigned short* __restrict__ T,
                                                   const int* __restrict__ row_ptr,
                                                   const int* __restrict__ col,
                                                   const float* __restrict__ r_in,
                                                   const float* __restrict__ b,
                                                   unsigned short* __restrict__ H) {
    int wave = threadIdx.x >> 6, lane = threadIdx.x & 63;
    int sub = lane >> 4, l16 = lane & 15;
    int node = blockIdx.x * 16 + wave * 4 + sub;
    if (node >= NN) return;
    int beg = row_ptr[node], end = row_ptr[node + 1];
    float a0 = 0.f, a1 = 0.f, a2 = 0.f, a3 = 0.f, a4 = 0.f, a5 = 0.f, a6 = 0.f, a7 = 0.f;
    for (int base = beg; base < end; base += 16) {
        int m = end - base; if (m > 16) m = 16;
        int myidx = (l16 < m) ? col[base + l16] : 0;
        int j = 0;
        for (; j + 8 <= m; j += 8) {
            uint4 v[8];
#pragma unroll
            for (int q = 0; q < 8; ++q) {
                int s = __shfl(myidx, (sub << 4) | (j + q));
                v[q] = *(const uint4*)(T + (size_t)s * DD + l16 * 8);
            }
#pragma unroll
            for (int q = 0; q < 8; ++q) {
                a0 += bf2f(v[q].x & 0xffff); a1 += bf2f(v[q].x >> 16);
                a2 += bf2f(v[q].y & 0xffff); a3 += bf2f(v[q].y >> 16);
                a4 += bf2f(v[q].z & 0xffff); a5 += bf2f(v[q].z >> 16);
                a6 += bf2f(v[q].w & 0xffff); a7 += bf2f(v[q].w >> 16);
            }
        }
        for (; j + 4 <= m; j += 4) {
            uint4 v[4];
#pragma unroll
            for (int q = 0; q < 4; ++q) {
                int s = __shfl(myidx, (sub << 4) | (j + q));
                v[q] = *(const uint4*)(T + (size_t)s * DD + l16 * 8);
            }
#pragma unroll
            for (int q = 0; q < 4; ++q) {
                a0 += bf2f(v[q].x & 0xffff); a1 += bf2f(v[q].x >> 16);
                a2 += bf2f(v[q].y & 0xffff); a3 += bf2f(v[q].y >> 16);
                a4 += bf2f(v[q].z & 0xffff); a5 += bf2f(v[q].z >> 16);
                a6 += bf2f(v[q].w & 0xffff); a7 += bf2f(v[q].w >> 16);
            }
        }
        for (; j < m; ++j) {
            int s0 = __shfl(myidx, (sub << 4) | j);
            uint4 v0 = *(const uint4*)(T + (size_t)s0 * DD + l16 * 8);
            a0 += bf2f(v0.x & 0xffff); a1 += bf2f(v0.x >> 16);
            a2 += bf2f(v0.y & 0xffff); a3 += bf2f(v0.y >> 16);
            a4 += bf2f(v0.z & 0xffff); a5 += bf2f(v0.z >> 16);
            a6 += bf2f(v0.w & 0xffff); a7 += bf2f(v0.w >> 16);
        }
    }
    float rv = r_in[node];
    float4 bl = *(const float4*)(b + l16 * 8);
    float4 bh = *(const float4*)(b + l16 * 8 + 4);
    uint4 w;
    w.x = (unsigned int)f2bf(a0 * rv + bl.x) | ((unsigned int)f2bf(a1 * rv + bl.y) << 16);
    w.y = (unsigned int)f2bf(a2 * rv + bl.z) | ((unsigned int)f2bf(a3 * rv + bl.w) << 16);
    w.z = (unsigned int)f2bf(a4 * rv + bh.x) | ((unsigned int)f2bf(a5 * rv + bh.y) << 16);
    w.w = (unsigned int)f2bf(a6 * rv + bh.z) | ((unsigned int)f2bf(a7 * rv + bh.w) << 16);
    *(uint4*)(H + (size_t)node * DD + l16 * 8) = w;
}

// ---- MFMA MLP: P[n] = softmax(relu(h2[n]@dW + db)@oW + ob) ----
__global__ __launch_bounds__(256) void k_mlp_mfma(const unsigned short* __restrict__ H2,
                                                  const unsigned short* __restrict__ BTd,
                                                  const float* __restrict__ db,
                                                  const float* __restrict__ oW,
                                                  const float* __restrict__ ob,
                                                  float* __restrict__ P) {
    __shared__ unsigned short As[64][136];
    __shared__ unsigned short Bs[128][136];
    int tid = threadIdx.x, lane = tid & 63, wave = tid >> 6;
    int quad = lane >> 4, l16 = lane & 15;
    int row0 = blockIdx.x * 64;
#pragma unroll
    for (int p = 0; p < 4; ++p) {
        int fid = tid + p * 256;
        int r = fid >> 4, c = fid & 15;
        int gr = row0 + r; if (gr > NN - 1) gr = NN - 1;
        *(uint4*)&As[r][c * 8] = *(const uint4*)(H2 + (size_t)gr * DD + c * 8);
    }
    short8 af[4];
    floatx4 acc[16];
#pragma unroll
    for (int i = 0; i < 16; ++i) acc[i] = (floatx4){0.f, 0.f, 0.f, 0.f};

    for (int ch = 0; ch < 2; ++ch) {
        __syncthreads();
#pragma unroll
        for (int p = 0; p < 8; ++p) {
            int fid = tid + p * 256;
            int r = fid >> 4, c = fid & 15;
            *(uint4*)&Bs[r][c * 8] = *(const uint4*)(BTd + (size_t)(ch * 128 + r) * DD + c * 8);
        }
        __syncthreads();
        if (ch == 0) {
#pragma unroll
            for (int ks = 0; ks < 4; ++ks)
                af[ks] = *(const short8*)&As[wave * 16 + l16][ks * 32 + quad * 8];
        }
#pragma unroll
        for (int ks = 0; ks < 4; ++ks) {
#pragma unroll
            for (int nt = 0; nt < 8; ++nt) {
                short8 bf = *(const short8*)&Bs[nt * 16 + l16][ks * 32 + quad * 8];
                acc[ch * 8 + nt] =
                    __builtin_amdgcn_mfma_f32_16x16x32_bf16(af[ks], bf, acc[ch * 8 + nt], 0, 0, 0);
            }
        }
    }
    int rbase = row0 + wave * 16 + quad * 4;
#pragma unroll
    for (int r = 0; r < 4; ++r) {
        float p0 = 0.f, p1 = 0.f;
#pragma unroll
        for (int ch = 0; ch < 2; ++ch) {
#pragma unroll
            for (int nt = 0; nt < 8; ++nt) {
                int colc = ch * 128 + nt * 16 + l16;
                float h = acc[ch * 8 + nt][r] + db[colc];
                h = fmaxf(h, 0.f);
                p0 += h * oW[2 * colc];
                p1 += h * oW[2 * colc + 1];
            }
        }
#pragma unroll
        for (int m = 8; m >= 1; m >>= 1) {
            p0 += __shfl_xor(p0, m, 16);
            p1 += __shfl_xor(p1, m, 16);
        }
        if (l16 == 0) {
            int gr = rbase + r;
            if (gr < NN) {
                float l0 = p0 + ob[0], l1 = p1 + ob[1];
                float mx = fmaxf(l0, l1);
                float e0 = __expf(l0 - mx), e1 = __expf(l1 - mx);
                float inv = 1.f / (e0 + e1);
                float2 pr = {e0 * inv, e1 * inv};
                *(float2*)(P + 2 * gr) = pr;
            }
        }
    }
}

// ---- final gather ----
__global__ void k_gather(const int* __restrict__ sidx, const int* __restrict__ oe,
                         const float* __restrict__ P, float* __restrict__ out) {
    int i = blockIdx.x * 256 + threadIdx.x;
    if (i >= NS) return;
    int node = oe[sidx[i]];
    float2 v = *(const float2*)(P + 2 * node);
    *(float2*)(out + 2 * i) = v;
}

extern "C" void kernel_launch(void* const* d_in, const int* in_sizes, int n_in,
                              void* d_out, int out_size, void* d_ws, size_t ws_size,
                              hipStream_t stream) {
    const float* node_state = (const float*)d_in[0];
    const int* ei   = (const int*)d_in[1];
    const int* oe   = (const int*)d_in[2];
    const int* sidx = (const int*)d_in[3];
    const float* W1 = (const float*)d_in[4];
    const float* b1 = (const float*)d_in[5];
    const float* W2 = (const float*)d_in[6];
    const float* b2 = (const float*)d_in[7];
    const float* dW = (const float*)d_in[8];
    const float* db = (const float*)d_in[9];
    const float* oW = (const float*)d_in[10];
    const float* ob = (const float*)d_in[11];
    float* out = (float*)d_out;

    char* ws = (char*)d_ws;
    size_t off = 0;
    auto carve = [&](size_t bytes) -> char* {
        char* p = ws + off;
        off = (off + bytes + 255) & ~(size_t)255;
        return p;
    };
    float* r       = (float*)carve((size_t)2 * NN * 4);
    int*   row_ptr = (int*)carve((size_t)(NN + 1) * 4);
    int*   col     = (int*)carve((size_t)NE * 4);
    unsigned int* P_hist = (unsigned int*)carve((size_t)2 * NBH * NW * 4);
    unsigned char* baseb = (unsigned char*)carve((size_t)NBH * NN);
    unsigned long long* status = (unsigned long long*)carve(64 * 8);
    unsigned short* t   = (unsigned short*)carve((size_t)NN * DD * 2);
    unsigned short* h   = (unsigned short*)carve((size_t)NN * DD * 2);
    unsigned short* BT1 = (unsigned short*)carve((size_t)DD * DD * 2);
    unsigned short* BT2 = (unsigned short*)carve((size_t)DD * DD * 2);
    unsigned short* BTd = (unsigned short*)carve((size_t)DD * NU * 2);
    float* P = (float*)t;   // alias: t dead after second aggregate

    float* r_out = r;
    float* r_in  = r + NN;

    // CSR build — no global atomics; mid-chain fused into one dispatch
    k_hist<<<dim3(NBH, 2), 256, 0, stream>>>(ei, P_hist, status);
    k_mid<<<256, 256, 0, stream>>>(P_hist, r, W1, W2, dW, BT1, BT2, BTd,
                                   row_ptr, baseb, status);

    // bucket + layer-1 GEMM in one wide kernel (independent given k_mid)
    k_gemm1_bucket<<<NBH + NB64, 256, 0, stream>>>(node_state, r_out, BT1, t,
                                                   ei, row_ptr, baseb, col);
    k_aggregate<<<(NN + 15) / 16, 256, 0, stream>>>(t, row_ptr, col, r_in, b1, h);

    // layer 2
    k_gemm_bf<<<NB64, 256, 0, stream>>>(h, r_out, BT2, t);
    k_aggregate<<<(NN + 15) / 16, 256, 0, stream>>>(t, row_ptr, col, r_in, b2, h);

    // per-node MLP + softmax, then gather
    k_mlp_mfma<<<NB64, 256, 0, stream>>>(h, BTd, db, oW, ob, P);
    k_gather<<<(NS + 255) / 256, 256, 0, stream>>>(sidx, oe, P, out);
}